// Round 8
// baseline (368.977 us; speedup 1.0000x reference)
//
#include <hip/hip_runtime.h>
#include <hip/hip_bf16.h>
#include <stdint.h>

// ---------------------------------------------------------------------------
// FusionNet: seq[t,d] = sum_r w[r]*(imu1[t]@A[r,:,d])*(vid1[t]@Bv[r,:,d]) + fb[d]
//            out[t]   = (relu(seq@W1 + b1) @ W2 + b2) / (anthro0*anthro1)
//
// History:
//  R0 (153us): 16x16x32 MFMA, LDS tables (95KB), 512thr/(512,2), 20% occ.
//  R1-R5: launch_bounds/persistent-loop occupancy attempts -> spills.
//      Lessons: 2nd launch_bounds arg = min BLOCKS/CU; no multi-tile loops.
//  R6 (130us, champion): swapped MFMA acc=[rank][token], shfl chains 8x
//      down, VGPR 128 no spill, 0 bank conflicts. Still 1 blk/CU (89.9KB
//      LDS), 2 waves/SIMD, all pipes <27% -> latency-bound.
//  R7: 32x32x16 + (512,1) -> allocator still caps at 128 VGPR -> 90MB
//      spill. Lesson: 128 VGPR is the practical per-wave ceiling; design
//      within it.
//  R8: occupancy via LDS diet, not registers: stage weight tables in TWO
//      d-halves (d0-4, d5-9) through a half-sized buffer. LDS 89.9->48.9KB
//      -> 3 blocks/CU = 24 waves/CU (3x latency hiding). Extra barrier +
//      40KB restage per block is covered by co-resident blocks.
//      sched_barrier(0) before restage prevents load-hoisting into phase-0
//      compute (the R4/R5 register trap).
// ---------------------------------------------------------------------------

#define NTOK   262144      // B*S = 64*4096
#define FDIM   128
#define RANKN  16
#define FUSED  10
#define WTE    (FUSED*RANKN*FDIM)   // 20480 bf16 elements per full table
#define HWTE   (WTE/2)              // 10240 per d-half (d-outer => contiguous)
#define NEXTRA 1984        // f32: a0 160 | b0 160 | W1L 1280 | b1L 128 | w20 128 | w21 128

typedef unsigned short u16;
typedef __bf16 bf16x8 __attribute__((ext_vector_type(8)));
typedef float  f32x4  __attribute__((ext_vector_type(4)));

static __device__ __forceinline__ u16 f2bf(float f) {
    union { float f; uint32_t u; } c; c.f = f;
    uint32_t u = c.u + 0x7FFFu + ((c.u >> 16) & 1u);   // RNE
    return (u16)(u >> 16);
}

// ---------------------------------------------------------------------------
// Prep: bf16 weight tables in MFMA fragment order (d outermost, so d-halves
// are contiguous):
//   elem (d, kk, lane=quad*16+r, j) = factor[r, 0, k+1, d],  k = kk*32+quad*8+j
// Extras (f32):
//   a0/b0 [d][16]: "ones"-row constants (rank r at slot r)
//   W1L  [(g*4+quad)*10+d][4]: W1[d][quad*32+g*4+i]
//   b1L  [(g*4+quad)][4]: b1' = b1 + fb@W1;  w20/w21: W2 columns
// fusion_weights folded into imu side.
// ---------------------------------------------------------------------------
__global__ void prep_kernel(const float* __restrict__ imf, const float* __restrict__ vif,
                            const float* __restrict__ fw,  const float* __restrict__ fb,
                            const float* __restrict__ W1,  const float* __restrict__ b1,
                            const float* __restrict__ W2,
                            u16* __restrict__ wImu, u16* __restrict__ wVid,
                            float* __restrict__ extra) {
    int idx = blockIdx.x * blockDim.x + threadIdx.x;
    float* a0  = extra;
    float* b0  = extra + 160;
    float* W1L = extra + 320;
    float* b1L = extra + 1600;
    float* w20 = extra + 1728;
    float* w21 = extra + 1856;

    if (idx < FUSED * RANKN * FDIM) {           // 20480
        int k = idx & 127;
        int r = (idx >> 7) & 15;
        int d = idx >> 11;
        int src = r * ((FDIM + 1) * FUSED) + (k + 1) * FUSED + d;  // factor[r,0,k+1,d]
        int kk   = k >> 5;
        int quad = (k >> 3) & 3;
        int j    = k & 7;
        int lane = quad * 16 + r;
        int dst  = ((d * 4 + kk) * 64 + lane) * 8 + j;
        wImu[dst] = f2bf(fw[r] * imf[src]);
        wVid[dst] = f2bf(vif[src]);
    }
    if (idx < RANKN * FUSED) {                  // 160, layout [d][16 ranks]
        int r = idx & 15, d = idx >> 4;
        int src = r * ((FDIM + 1) * FUSED) + d; // factor[r,0,0,d]
        a0[idx] = fw[r] * imf[src];
        b0[idx] = vif[src];
    }
    if (idx < 1280) {                           // W1L[(g*4+q)*10+d][i] = W1[d][q*32+g*4+i]
        int i = idx & 3;
        int t = idx >> 2;                       // 0..319
        int d = t % 10;
        int gq = t / 10;                        // 0..31
        int g = gq >> 2, q = gq & 3;
        int j = q * 32 + g * 4 + i;
        W1L[idx] = W1[d * FDIM + j];
    }
    if (idx < FDIM) {                           // b1L / w20 / w21 in gq layout
        int i = idx & 3;
        int gq = idx >> 2;
        int g = gq >> 2, q = gq & 3;
        int j = q * 32 + g * 4 + i;
        float acc = b1[j];
        #pragma unroll
        for (int d = 0; d < FUSED; ++d) acc += fb[d] * W1[d * FDIM + j];
        b1L[idx] = acc;
        w20[idx] = W2[2 * j];
        w21[idx] = W2[2 * j + 1];
    }
}

// ---------------------------------------------------------------------------
// Main: 512 threads = 8 waves, (512,2), one 16-token tile per wave.
// Weight tables staged in two d-halves through a 40KB LDS buffer ->
// 48.9KB total -> 3 blocks/CU co-resident.
// ---------------------------------------------------------------------------
__launch_bounds__(512, 2)
__global__ void fusion_main(const float* __restrict__ imu, const float* __restrict__ vid,
                            const float* __restrict__ anthro,
                            const u16* __restrict__ wImuG, const u16* __restrict__ wVidG,
                            const float* __restrict__ extraG,
                            const float* __restrict__ b2g,
                            float* __restrict__ out) {
    extern __shared__ char smem[];
    u16* sFI = (u16*)smem;                // [5 d][4 kk][64 lane][8] bf16 (half)
    u16* sFV = sFI + HWTE;
    float* sX   = (float*)(sFV + HWTE);   // extras block (1984 f32)
    float* sA0  = sX;                     // [10 d][16]
    float* sB0  = sX + 160;
    float* sW1L = sX + 320;               // [32 gq][10 d][4]
    float* sB1L = sX + 1600;              // [32 gq][4]
    float* sW20 = sX + 1728;
    float* sW21 = sX + 1856;

    // ---- stage phase 0: d-half 0 of both tables + extras ----
    {
        const uint4* srcI = (const uint4*)wImuG;
        const uint4* srcV = (const uint4*)wVidG;
        const uint4* srcX = (const uint4*)extraG;
        uint4* dstI = (uint4*)sFI;
        uint4* dstV = (uint4*)sFV;
        uint4* dstX = (uint4*)sX;
        for (int i = threadIdx.x; i < HWTE / 8; i += blockDim.x) { // 1280
            dstI[i] = srcI[i];
            dstV[i] = srcV[i];
        }
        for (int i = threadIdx.x; i < NEXTRA / 4; i += blockDim.x) // 496
            dstX[i] = srcX[i];
    }

    const int lane = threadIdx.x & 63;
    const int quad = lane >> 4;          // acc rows: ranks quad*4..quad*4+3
    const int r16  = lane & 15;          // token column
    const int wid  = threadIdx.x >> 6;
    const int t0   = (blockIdx.x * 8 + wid) * 16;   // one tile per wave

    const int bidx = t0 >> 12;           // S = 4096
    const float invwh = 1.0f / (anthro[2 * bidx] * anthro[2 * bidx + 1]);
    const float b20 = b2g[0], b21 = b2g[1];

    // ---- token fragments (B operand): lane holds T[n=r16][k=quad*8+j] ----
    bf16x8 aI[4], aV[4];
    {
        const float* baseI = imu + (size_t)(t0 + r16) * FDIM + quad * 8;
        const float* baseV = vid + (size_t)(t0 + r16) * FDIM + quad * 8;
        #pragma unroll
        for (int kk = 0; kk < 4; ++kk) {
            f32x4 v0 = *(const f32x4*)(baseI + kk * 32);
            f32x4 v1 = *(const f32x4*)(baseI + kk * 32 + 4);
            f32x4 w0 = *(const f32x4*)(baseV + kk * 32);
            f32x4 w1 = *(const f32x4*)(baseV + kk * 32 + 4);
            bf16x8 a, b;
            #pragma unroll
            for (int j = 0; j < 4; ++j) {
                a[j] = (__bf16)v0[j]; a[j + 4] = (__bf16)v1[j];
                b[j] = (__bf16)w0[j]; b[j + 4] = (__bf16)w1[j];
            }
            aI[kk] = a;
            aV[kk] = b;
        }
    }
    __syncthreads();

    const bf16x8* fragI = (const bf16x8*)(const void*)sFI;
    const bf16x8* fragV = (const bf16x8*)(const void*)sFV;

    float seqv[FUSED];

    // ---- phase 0 compute: d = 0..4 ----
    #pragma unroll
    for (int d = 0; d < 5; ++d) {
        f32x4 accU = {0.f, 0.f, 0.f, 0.f};
        f32x4 accV = {0.f, 0.f, 0.f, 0.f};
        #pragma unroll
        for (int kk = 0; kk < 4; ++kk) {
            accU = __builtin_amdgcn_mfma_f32_16x16x32_bf16(fragI[(d * 4 + kk) * 64 + lane], aI[kk], accU, 0, 0, 0);
            accV = __builtin_amdgcn_mfma_f32_16x16x32_bf16(fragV[(d * 4 + kk) * 64 + lane], aV[kk], accV, 0, 0, 0);
        }
        f32x4 a0c = *(const f32x4*)(sA0 + d * 16 + quad * 4);
        f32x4 b0c = *(const f32x4*)(sB0 + d * 16 + quad * 4);
        float s = 0.f;
        #pragma unroll
        for (int reg = 0; reg < 4; ++reg)
            s += (accU[reg] + a0c[reg]) * (accV[reg] + b0c[reg]);
        s += __shfl_xor(s, 16, 64);
        s += __shfl_xor(s, 32, 64);
        seqv[d] = s;
    }
    __syncthreads();                     // all waves done with half 0

    // ---- stage phase 1: d-half 1 (do not hoist into phase-0 compute) ----
    __builtin_amdgcn_sched_barrier(0);
    {
        const uint4* srcI = (const uint4*)(wImuG + HWTE);
        const uint4* srcV = (const uint4*)(wVidG + HWTE);
        uint4* dstI = (uint4*)sFI;
        uint4* dstV = (uint4*)sFV;
        for (int i = threadIdx.x; i < HWTE / 8; i += blockDim.x) { // 1280
            dstI[i] = srcI[i];
            dstV[i] = srcV[i];
        }
    }
    __syncthreads();

    // ---- phase 1 compute: d = 5..9 ----
    #pragma unroll
    for (int d = 0; d < 5; ++d) {
        f32x4 accU = {0.f, 0.f, 0.f, 0.f};
        f32x4 accV = {0.f, 0.f, 0.f, 0.f};
        #pragma unroll
        for (int kk = 0; kk < 4; ++kk) {
            accU = __builtin_amdgcn_mfma_f32_16x16x32_bf16(fragI[(d * 4 + kk) * 64 + lane], aI[kk], accU, 0, 0, 0);
            accV = __builtin_amdgcn_mfma_f32_16x16x32_bf16(fragV[(d * 4 + kk) * 64 + lane], aV[kk], accV, 0, 0, 0);
        }
        f32x4 a0c = *(const f32x4*)(sA0 + (5 + d) * 16 + quad * 4);
        f32x4 b0c = *(const f32x4*)(sB0 + (5 + d) * 16 + quad * 4);
        float s = 0.f;
        #pragma unroll
        for (int reg = 0; reg < 4; ++reg)
            s += (accU[reg] + a0c[reg]) * (accV[reg] + b0c[reg]);
        s += __shfl_xor(s, 16, 64);
        s += __shfl_xor(s, 32, 64);
        seqv[5 + d] = s;
    }

    // ---- MLP from LDS: lane = token r16, j-columns quad*32+g*4..+3 ----
    float o0 = 0.f, o1 = 0.f;
    #pragma unroll
    for (int g = 0; g < 8; ++g) {
        const int gq = g * 4 + quad;
        f32x4 h = *(const f32x4*)(sB1L + gq * 4);
        #pragma unroll
        for (int d = 0; d < FUSED; ++d) {
            f32x4 wv = *(const f32x4*)(sW1L + (gq * 10 + d) * 4);
            #pragma unroll
            for (int i = 0; i < 4; ++i) h[i] += seqv[d] * wv[i];
        }
        f32x4 w20v = *(const f32x4*)(sW20 + gq * 4);
        f32x4 w21v = *(const f32x4*)(sW21 + gq * 4);
        #pragma unroll
        for (int i = 0; i < 4; ++i) {
            float hr = fmaxf(h[i], 0.f);
            o0 += hr * w20v[i];
            o1 += hr * w21v[i];
        }
    }
    o0 += __shfl_xor(o0, 16, 64);
    o0 += __shfl_xor(o0, 32, 64);
    o1 += __shfl_xor(o1, 16, 64);
    o1 += __shfl_xor(o1, 32, 64);

    if (lane < 16) {
        const int t = t0 + r16;
        float2 o = make_float2((o0 + b20) * invwh, (o1 + b21) * invwh);
        *(float2*)(out + 2 * t) = o;
    }
}

// ---------------------------------------------------------------------------
extern "C" void kernel_launch(void* const* d_in, const int* in_sizes, int n_in,
                              void* d_out, int out_size, void* d_ws, size_t ws_size,
                              hipStream_t stream) {
    const float* imu    = (const float*)d_in[0];
    const float* vid    = (const float*)d_in[1];
    const float* anthro = (const float*)d_in[2];
    const float* imf    = (const float*)d_in[3];
    const float* vif    = (const float*)d_in[4];
    const float* fw     = (const float*)d_in[5];
    const float* fb     = (const float*)d_in[6];
    const float* W1     = (const float*)d_in[7];
    const float* b1     = (const float*)d_in[8];
    const float* W2     = (const float*)d_in[9];
    const float* b2     = (const float*)d_in[10];
    float* out = (float*)d_out;

    // workspace: [wImu u16 20480][wVid u16 20480][extras f32 1984]
    u16* wImu = (u16*)d_ws;
    u16* wVid = wImu + WTE;
    float* extra = (float*)(wVid + WTE);

    prep_kernel<<<80, 256, 0, stream>>>(imf, vif, fw, fb, W1, b1, W2,
                                        wImu, wVid, extra);

    const size_t smem = (size_t)(2 * HWTE) * sizeof(u16)
                      + (size_t)NEXTRA * sizeof(float);    // 48896 B
    // 2048 blocks x 8 waves x 16 tokens = 262144 tokens exactly
    fusion_main<<<2048, 512, smem, stream>>>(imu, vid, anthro, wImu, wVid,
                                             extra, b2, out);
}